// Round 15
// baseline (133.072 us; speedup 1.0000x reference)
//
#include <hip/hip_runtime.h>

// HarmonicConvolutionFilter on MI355X (round 15 — NREP=4 A/B of round-14 body).
// x: [B=4, S=1024, F=512, C=4] f32;  W: [5, K=4, C=4, O=4] f32;  out: [B,S,F,4] f32
//
// Channel history: r10 (r6 body, NREP4) dispatch=85us -> T=21.3us.
// r13 (r11 body, NREP4) dispatch=114us -> hoist+fuse falsified.
// r14 (pk_fma + global high-half, plain) -> dur_us 96.3, unreadable vs
// cross-session drift. This round: r14 body in the NREP=4 harness.
//   confirmed: dispatch 62-72us (T 15.5-18us), conflicts ~3.2M
//   null (>=80us): pk_fma didn't emit or issue-model wrong -> r16 pivots.

#define TS    2
#define NTAP  5
#define FB    512
#define SB    1024
#define BB    4
#define NROW  (TS + 4)
#define ROWP  544
#define NREP  4

typedef float vfloat2 __attribute__((ext_vector_type(2)));
typedef float vfloat4 __attribute__((ext_vector_type(4)));

__device__ __forceinline__ void nt_store4(float4 v, float4* p) {
    vfloat4 raw = { v.x, v.y, v.z, v.w };
    __builtin_nontemporal_store(raw, (vfloat4*)p);
}

__device__ __forceinline__ int swz(int f) { return f + (f >> 4); }

// one tap, one 6-row window, packed o-pairs: 8 v_pk_fma_f32 per j-row
__device__ __forceinline__ void fma_tap_pk(vfloat2 a01[TS], vfloat2 a23[TS],
                                           const float4* xw, int t,
                                           const vfloat2 w[8]) {
#pragma unroll
    for (int j = 0; j < TS; ++j) {
        const float4 xv = xw[j + t];
        vfloat2 xx;
        xx = (vfloat2){xv.x, xv.x}; a01[j] += xx * w[0]; a23[j] += xx * w[1];
        xx = (vfloat2){xv.y, xv.y}; a01[j] += xx * w[2]; a23[j] += xx * w[3];
        xx = (vfloat2){xv.z, xv.z}; a01[j] += xx * w[4]; a23[j] += xx * w[5];
        xx = (vfloat2){xv.w, xv.w}; a01[j] += xx * w[6]; a23[j] += xx * w[7];
    }
}

// gather 6-row window for harmonic column g from LDS, run 5 taps
// weights JIT-loaded per tap (SGPR-friendly, r13 lesson)
__device__ __forceinline__ void accum_harm_pk(const float4* lx, int g,
                                              const float* __restrict__ Wk,
                                              vfloat2 a01[TS], vfloat2 a23[TS]) {
    float4 xw[NROW];
    const int gs = swz(g);
#pragma unroll
    for (int r = 0; r < NROW; ++r) xw[r] = lx[r * ROWP + gs];
#pragma unroll
    for (int t = 0; t < NTAP; ++t) {
        const vfloat2* wp = (const vfloat2*)(Wk + t * 64);  // uniform -> s_load
        vfloat2 w[8];
#pragma unroll
        for (int i = 0; i < 8; ++i) w[i] = wp[i];
        fma_tap_pk(a01, a23, xw, t, w);
    }
}

__global__ __launch_bounds__(256, 3)
void harmonic_conv_kernel(const float* __restrict__ x,
                          const float* __restrict__ W,
                          float* __restrict__ out) {
    __shared__ float4 lx[NROW * ROWP];   // 51 KB -> 3 blocks/CU

    const int bid  = blockIdx.x;
    const int work = ((bid & 7) << 8) | (bid >> 3);   // XCD-contiguous chunks
    const int b    = work >> 9;
    const int s0   = (work & 511) * TS;
    const int tid  = threadIdx.x;

    const float4* xb = (const float4*)x + (size_t)b * SB * FB;
    float4*       ob = (float4*)out + (size_t)b * SB * FB;

#pragma unroll 1
    for (int rep = 0; rep < NREP; ++rep) {
        // ---- high half (f = tid+256, m=1): global-direct, issued EARLY ----
        float4 xhg[NROW];
#pragma unroll
        for (int r = 0; r < NROW; ++r) {
            const int sp = s0 + r - 2;                // block-uniform predicate
            xhg[r] = (sp >= 0 && sp < SB) ? xb[(size_t)sp * FB + (tid + 256)]
                                          : make_float4(0.f, 0.f, 0.f, 0.f);
        }

        // ---- stage 6 rows x 512 f into LDS (coalesced); pad rows -> 0 ----
#pragma unroll
        for (int i = 0; i < NROW * FB / 256; ++i) {   // 12 iters
            const int n  = i * 256 + tid;
            const int r  = n >> 9;
            const int f  = n & (FB - 1);
            const int sp = s0 + r - 2;
            float4 v = make_float4(0.f, 0.f, 0.f, 0.f);
            if (sp >= 0 && sp < SB) v = xb[(size_t)sp * FB + f];
            lx[r * ROWP + swz(f)] = v;
        }
        __syncthreads();

        vfloat2 a01[TS], a23[TS];

        // ---- high half compute (data already in registers) ----
#pragma unroll
        for (int j = 0; j < TS; ++j) { a01[j] = (vfloat2){0.f, 0.f}; a23[j] = (vfloat2){0.f, 0.f}; }
#pragma unroll
        for (int t = 0; t < NTAP; ++t) {
            const vfloat2* wp = (const vfloat2*)(W + t * 64);   // m=1 slice
            vfloat2 w[8];
#pragma unroll
            for (int i = 0; i < 8; ++i) w[i] = wp[i];
            fma_tap_pk(a01, a23, xhg, t, w);
        }
#pragma unroll
        for (int j = 0; j < TS; ++j)
            nt_store4(make_float4(a01[j].x, a01[j].y, a23[j].x, a23[j].y),
                      &ob[(size_t)(s0 + j) * FB + (tid + 256)]);

        // ---- low half: f = tid, harmonics m=1..4 from LDS ----
#pragma unroll
        for (int j = 0; j < TS; ++j) { a01[j] = (vfloat2){0.f, 0.f}; a23[j] = (vfloat2){0.f, 0.f}; }
        accum_harm_pk(lx, tid,     W,      a01, a23);             // m=1
        accum_harm_pk(lx, tid * 2, W + 16, a01, a23);             // m=2
        if (tid * 3 < FB) accum_harm_pk(lx, tid * 3, W + 32, a01, a23);   // m=3
        if (tid * 4 < FB) accum_harm_pk(lx, tid * 4, W + 48, a01, a23);   // m=4
#pragma unroll
        for (int j = 0; j < TS; ++j)
            nt_store4(make_float4(a01[j].x, a01[j].y, a23[j].x, a23[j].y),
                      &ob[(size_t)(s0 + j) * FB + tid]);

        // reps must not race (next stage overwrites lx) and must not be elided
        __syncthreads();
        asm volatile("" ::: "memory");
    }
}

extern "C" void kernel_launch(void* const* d_in, const int* in_sizes, int n_in,
                              void* d_out, int out_size, void* d_ws, size_t ws_size,
                              hipStream_t stream) {
    const float* x = (const float*)d_in[0];
    const float* W = (const float*)d_in[1];
    float* out = (float*)d_out;
    const int nblocks = BB * (SB / TS);   // 2048
    harmonic_conv_kernel<<<nblocks, 256, 0, stream>>>(x, W, out);
}